// Round 2
// baseline (1550.148 us; speedup 1.0000x reference)
//
#include <hip/hip_runtime.h>
#include <cmath>
#include <cstdint>
#include <cstring>
#include <vector>
#include <algorithm>

#ifndef M_PI
#define M_PI 3.14159265358979323846
#endif

typedef float2 c2;
#define NLMN 5456   // sum_{l<16} (2l+1)^2
#define NLM  256    // sum_{l<16} (2l+1)

__device__ __forceinline__ c2 cmad(c2 acc, c2 a, c2 b) {
  acc.x = fmaf(a.x, b.x, fmaf(-a.y, b.y, acc.x));
  acc.y = fmaf(a.x, b.y, fmaf( a.y, b.x, acc.y));
  return acc;
}

// ---------------------------------------------------------------------------
// K1: xf1[row=(b*12+i)*64+z][m15] = (1/64) sum_a x[row][a] * e^{-2pi i a m/64}
__global__ void k_s2_fft(const float* __restrict__ x, c2* __restrict__ xf1,
                         const c2* __restrict__ dft64) {
  __shared__ float row[64];
  int r = blockIdx.x;
  row[threadIdx.x] = x[(size_t)r * 64 + threadIdx.x];
  __syncthreads();
  int m = threadIdx.x;
  if (m < 31) {
    float ax = 0.f, ay = 0.f;
    #pragma unroll
    for (int a = 0; a < 64; ++a) {
      c2 e = dft64[m * 64 + a];
      float v = row[a];
      ax = fmaf(v, e.x, ax); ay = fmaf(v, e.y, ay);
    }
    xf1[(size_t)r * 31 + m] = make_float2(ax * (1.f / 64.f), ay * (1.f / 64.f));
  }
}

// K2: wh[m15][io] = sum_j w[io][j] * tab[m15][j]
__global__ __launch_bounds__(256) void k_wfft(const float* __restrict__ w,
                       c2* __restrict__ wh, const c2* __restrict__ tab,
                       int IO, int J) {
  int t = blockIdx.x * blockDim.x + threadIdx.x;
  if (t >= 31 * IO) return;
  int m = t / IO, io = t - m * IO;
  float ax = 0.f, ay = 0.f;
  for (int j = 0; j < J; ++j) {
    float v = w[(size_t)io * J + j];
    c2 e = tab[m * J + j];
    ax = fmaf(v, e.x, ax); ay = fmaf(v, e.y, ay);
  }
  wh[t] = make_float2(ax, ay);
}

// K3: X1[lm][b*12+i] = sum_z cf1[l][m15][z] * xf1[(b*12+i)*64+z][m15]
__global__ __launch_bounds__(256) void k_X1(const c2* __restrict__ xf1,
                     c2* __restrict__ X1, const float* __restrict__ cf1,
                     const int* __restrict__ lm_l, const int* __restrict__ lm_m) {
  int t = blockIdx.x * blockDim.x + threadIdx.x;
  if (t >= NLM * 96) return;
  int lm = t / 96, bi = t - lm * 96;
  int l = lm_l[lm], m15 = lm_m[lm];
  const float* cf = cf1 + (size_t)(l * 31 + m15) * 64;
  const c2* xp = xf1 + (size_t)bi * 64 * 31 + m15;
  float ax = 0.f, ay = 0.f;
  #pragma unroll 8
  for (int z = 0; z < 64; ++z) {
    float wg = cf[z];
    c2 v = xp[(size_t)z * 31];
    ax = fmaf(wg, v.x, ax); ay = fmaf(wg, v.y, ay);
  }
  X1[t] = make_float2(ax, ay);
}

// K4: Z1[bo][lmn] = cp1[l][n15] * sum_i X1[lm][b][i] * wh1[n15][i*32+o]
__global__ __launch_bounds__(256) void k_Z1(const c2* __restrict__ X1,
                     const c2* __restrict__ wh1, c2* __restrict__ Z1,
                     const float* __restrict__ cp1,
                     const int* __restrict__ lmn_l, const int* __restrict__ lmn_m,
                     const int* __restrict__ lmn_n) {
  int t = blockIdx.x * blockDim.x + threadIdx.x;
  if (t >= 256 * NLMN) return;
  int bo = t / NLMN, lmn = t - bo * NLMN;
  int b = bo >> 5, o = bo & 31;
  int l = lmn_l[lmn], m15 = lmn_m[lmn], n15 = lmn_n[lmn];
  int lm = l * l + (m15 - 15 + l);
  float s = cp1[l * 31 + n15];
  c2 acc = make_float2(0.f, 0.f);
  const c2* xp = X1 + (size_t)(lm * 8 + b) * 12;
  const c2* wp = wh1 + (size_t)n15 * 384 + o;
  #pragma unroll
  for (int i = 0; i < 12; ++i) acc = cmad(acc, xp[i], wp[(size_t)i * 32]);
  Z1[t] = make_float2(acc.x * s, acc.y * s);
}

// ---------------------------------------------------------------------------
// K_SYN: fused scatter + 2D inverse DFT + bias.
// One block handles (bo, z0..z0+ZPB-1). freq computed into LDS from Z (L2-hot),
// then 31x31 -> 32x32 IDFT2, write out.
#define ZPB 8
#define ZCH 4   // 32 / ZPB
__global__ __launch_bounds__(256) void k_syn(const c2* __restrict__ Z,
                        float* __restrict__ out, const float* __restrict__ bias,
                        const c2* __restrict__ idft32, const float* __restrict__ cd,
                        int O) {
  __shared__ c2 fq[961];
  __shared__ c2 Tm[992];
  __shared__ c2 tab[992];
  int bo = blockIdx.x / ZCH;
  int z0 = (blockIdx.x % ZCH) * ZPB;
  int tid = threadIdx.x;
  for (int k = tid; k < 992; k += 256) tab[k] = idft32[k];
  float bv = bias[bo % O];
  const c2* Zbo = Z + (size_t)bo * NLMN;
  __syncthreads();

  for (int zi = 0; zi < ZPB; ++zi) {
    int z = z0 + zi;
    // ---- freq[mn] = sum_{l>=lmin} cd[l][z][mn] * Z[bo][lmn]
    for (int k = tid; k < 961; k += 256) {
      int m15 = k / 31, n15 = k - m15 * 31;
      int m = m15 - 15, n = n15 - 15;
      int am = m < 0 ? -m : m, an = n < 0 ? -n : n;
      int lmin = am > an ? am : an;
      float ax = 0.f, ay = 0.f;
      for (int l = lmin; l < 16; ++l) {
        float d = cd[(size_t)(l * 32 + z) * 961 + k];
        int b3 = (4 * l * l * l - l) / 3;           // sum_{j<l}(2j+1)^2
        c2 zv = Zbo[b3 + (m + l) * (2 * l + 1) + (n + l)];
        ax = fmaf(d, zv.x, ax); ay = fmaf(d, zv.y, ay);
      }
      fq[k] = make_float2(ax, ay);
    }
    __syncthreads();
    // ---- stage 1: Tm[m][q] = sum_n fq[m][n] * tab[n][q]
    {
      int mm = tid >> 4, qq = tid & 15;
      int m0 = mm, m1 = mm + 16;
      bool v1 = (m1 < 31);
      c2 a00 = make_float2(0, 0), a01 = a00, a10 = a00, a11 = a00;
      for (int n = 0; n < 31; ++n) {
        c2 f0 = fq[m0 * 31 + n];
        c2 f1 = v1 ? fq[m1 * 31 + n] : make_float2(0, 0);
        c2 t0 = tab[n * 32 + qq];
        c2 t1 = tab[n * 32 + qq + 16];
        a00 = cmad(a00, f0, t0); a01 = cmad(a01, f0, t1);
        a10 = cmad(a10, f1, t0); a11 = cmad(a11, f1, t1);
      }
      Tm[m0 * 32 + qq] = a00; Tm[m0 * 32 + qq + 16] = a01;
      if (v1) { Tm[m1 * 32 + qq] = a10; Tm[m1 * 32 + qq + 16] = a11; }
    }
    __syncthreads();
    // ---- stage 2: out[p][q] = Re sum_m tab[m][p] * Tm[m][q]  (+bias)
    {
      int pp = tid >> 4, qq = tid & 15;
      float r00 = 0, r01 = 0, r10 = 0, r11 = 0;
      for (int m = 0; m < 31; ++m) {
        c2 tp0 = tab[m * 32 + pp];
        c2 tp1 = tab[m * 32 + pp + 16];
        c2 q0 = Tm[m * 32 + qq];
        c2 q1 = Tm[m * 32 + qq + 16];
        r00 = fmaf(tp0.x, q0.x, fmaf(-tp0.y, q0.y, r00));
        r01 = fmaf(tp0.x, q1.x, fmaf(-tp0.y, q1.y, r01));
        r10 = fmaf(tp1.x, q0.x, fmaf(-tp1.y, q0.y, r10));
        r11 = fmaf(tp1.x, q1.x, fmaf(-tp1.y, q1.y, r11));
      }
      float* ob = out + ((size_t)bo * 32 + z) * 1024;
      ob[pp * 32 + qq] = r00 + bv;
      ob[pp * 32 + qq + 16] = r01 + bv;
      ob[(pp + 16) * 32 + qq] = r10 + bv;
      ob[(pp + 16) * 32 + qq + 16] = r11 + bv;
    }
    __syncthreads();  // Tm/fq reuse next z
  }
}

// ---------------------------------------------------------------------------
// K_FFT2: fused relu + 2D DFT (32x32 -> 31x31), one image per block.
// xf2[img][m15][n15] = (1/1024) sum_{a,g} relu(x1[img][a][g]) e^{-2pi i(am+gn)/32}
__global__ __launch_bounds__(256) void k_fft2(const float* __restrict__ x1,
                       c2* __restrict__ xf2, const c2* __restrict__ dft32) {
  __shared__ float f[1024];
  __shared__ c2 G[992];      // [a][n15]
  __shared__ c2 tab[992];    // [m15][a]  (row-major, for stage B broadcast)
  __shared__ c2 tabT[992];   // [a][n15]  (transposed, for stage A coalesced)
  int img = blockIdx.x;
  int tid = threadIdx.x;
  const float* xp = x1 + (size_t)img * 1024;
  for (int k = tid; k < 1024; k += 256) { float v = xp[k]; f[k] = v > 0.f ? v : 0.f; }
  for (int k = tid; k < 992; k += 256) {
    tab[k] = dft32[k];
    int a = k / 31, n = k - a * 31;
    tabT[k] = dft32[n * 32 + a];
  }
  __syncthreads();
  // stage A: G[a][n] = sum_g f[a][g] * e^{-2pi i g(n-15)/32}
  for (int k = tid; k < 992; k += 256) {
    int a = k / 31, n = k - a * 31;
    const float* fr = f + a * 32;
    float ax = 0.f, ay = 0.f;
    #pragma unroll
    for (int g2 = 0; g2 < 32; ++g2) {
      c2 e = tabT[g2 * 31 + n];
      ax = fmaf(fr[g2], e.x, ax); ay = fmaf(fr[g2], e.y, ay);
    }
    G[k] = make_float2(ax, ay);
  }
  __syncthreads();
  // stage B: F[m][n] = (1/1024) sum_a e^{-2pi i a(m-15)/32} * G[a][n]
  c2* op = xf2 + (size_t)img * 961;
  for (int k = tid; k < 961; k += 256) {
    int m = k / 31, n = k - m * 31;
    const c2* tm2 = tab + m * 32;
    c2 acc = make_float2(0.f, 0.f);
    #pragma unroll
    for (int a = 0; a < 32; ++a) acc = cmad(acc, tm2[a], G[a * 31 + n]);
    op[k] = make_float2(acc.x * (1.f / 1024.f), acc.y * (1.f / 1024.f));
  }
}

// K9: X2[(b*32+i)][lmn] = sum_z cw2[l][z][mn] * xf2[bi][z][mn]
__global__ __launch_bounds__(256) void k_X2(const c2* __restrict__ xf2,
                     c2* __restrict__ X2, const float* __restrict__ cw2,
                     const int* __restrict__ lmn_l, const int* __restrict__ lmn_m,
                     const int* __restrict__ lmn_n, int total) {
  int t = blockIdx.x * blockDim.x + threadIdx.x;
  if (t >= total) return;
  int lmn = t % NLMN;
  int bi = t / NLMN;
  int l = lmn_l[lmn], m15 = lmn_m[lmn], n15 = lmn_n[lmn];
  int mn = m15 * 31 + n15;
  const c2* xp = xf2 + (size_t)bi * 32 * 961 + mn;
  const float* cw = cw2 + (size_t)l * 32 * 961 + mn;
  float ax = 0.f, ay = 0.f;
  for (int z = 0; z < 32; ++z) {
    float wg = cw[(size_t)z * 961];
    c2 v = xp[(size_t)z * 961];
    ax = fmaf(wg, v.x, ax); ay = fmaf(wg, v.y, ay);
  }
  X2[(size_t)bi * NLMN + lmn] = make_float2(ax, ay);
}

// K10: U[bo][lmk] = sum_i X2[b][i][lmk] * wh2[k15][i*64+o]
__global__ __launch_bounds__(256) void k_U(const c2* __restrict__ X2,
                    const c2* __restrict__ wh2, c2* __restrict__ U,
                    const int* __restrict__ lmn_n, int total) {
  int t = blockIdx.x * blockDim.x + threadIdx.x;
  if (t >= total) return;
  int lmk = t % NLMN;
  int bo = t / NLMN;
  int b = bo >> 6, o = bo & 63;
  int k15 = lmn_n[lmk];
  const c2* xp = X2 + (size_t)b * 32 * NLMN + lmk;
  const c2* wp = wh2 + (size_t)k15 * 2048 + o;
  c2 acc = make_float2(0.f, 0.f);
  #pragma unroll 8
  for (int i = 0; i < 32; ++i) acc = cmad(acc, xp[(size_t)i * NLMN], wp[(size_t)i * 64]);
  U[t] = acc;
}

// K11: Z2[bo][lmn] = sum_k U[bo][lmk] * cp2[l][k15][n15]
__global__ __launch_bounds__(256) void k_Z2(const c2* __restrict__ U,
                     c2* __restrict__ Z2, const float* __restrict__ cp2,
                     const int* __restrict__ lmn_l, const int* __restrict__ lmn_m,
                     const int* __restrict__ lmn_n, const int* __restrict__ base3,
                     int total) {
  int t = blockIdx.x * blockDim.x + threadIdx.x;
  if (t >= total) return;
  int lmn = t % NLMN;
  int bo = t / NLMN;
  int l = lmn_l[lmn], m15 = lmn_m[lmn], n15 = lmn_n[lmn];
  int tl = 2 * l + 1;
  const c2* up = U + (size_t)bo * NLMN + base3[l] + (m15 - 15 + l) * tl;
  const float* cp = cp2 + ((size_t)l * 31 + (15 - l)) * 31 + n15;
  float ax = 0.f, ay = 0.f;
  for (int kk = 0; kk < tl; ++kk) {
    float s = cp[(size_t)kk * 31];
    c2 uv = up[kk];
    ax = fmaf(s, uv.x, ax); ay = fmaf(s, uv.y, ay);
  }
  Z2[t] = make_float2(ax, ay);
}

// ---------------------------------------------------------------------------
namespace {

struct DC {
  c2 *dft64, *dft32, *idft32;
  float *cf1, *cp1, *cd1, *cw2, *cp2;
  int *base3, *lmn_l, *lmn_m, *lmn_n, *lm_l, *lm_m;
};
DC g{};
void* g_base = nullptr;
double s_fact[64];

void wig_d(int l, double beta, double* out) {
  int n = 2 * l + 1;
  double cb = cos(beta * 0.5), sb = sin(beta * 0.5);
  for (int a = 0; a < n; ++a) {
    int mp = a - l;
    for (int b = 0; b < n; ++b) {
      int m = b - l;
      double pref = sqrt(s_fact[l + mp] * s_fact[l - mp] * s_fact[l + m] * s_fact[l - m]);
      int smin = std::max(0, m - mp);
      int smax = std::min(l + m, l - mp);
      double sum = 0.0;
      for (int s = smin; s <= smax; ++s) {
        double denom = s_fact[l + m - s] * s_fact[s] * s_fact[mp - m + s] * s_fact[l - mp - s];
        double sign = ((mp - m + s) & 1) ? -1.0 : 1.0;
        sum += sign / denom * std::pow(cb, 2 * l + m - mp - 2 * s)
                            * std::pow(sb, mp - m + 2 * s);
      }
      out[a * n + b] = pref * sum;
    }
  }
}

void quad_w(int b, double* w) {
  for (int k = 0; k < 2 * b; ++k) {
    double th = M_PI * (2.0 * k + 1.0) / (4.0 * b);
    double s = 0;
    for (int j = 0; j < b; ++j) s += sin(th * (2 * j + 1)) / (2 * j + 1);
    w[k] = 2.0 / b * sin(th) * s;
  }
}

void build_and_upload() {
  if (g_base) return;
  s_fact[0] = 1;
  for (int i = 1; i < 64; ++i) s_fact[i] = s_fact[i - 1] * i;

  size_t pos = 0;
  auto al = [&](size_t b) { pos = (pos + 15) & ~(size_t)15; size_t r = pos; pos += b; return r; };
  size_t o_dft64 = al(31 * 64 * sizeof(c2));
  size_t o_dft32 = al(31 * 32 * sizeof(c2));
  size_t o_idft32 = al(31 * 32 * sizeof(c2));
  size_t o_cf1 = al(16 * 31 * 64 * 4);
  size_t o_cp1 = al(16 * 31 * 4);
  size_t o_cd1 = al((size_t)16 * 32 * 961 * 4);
  size_t o_cw2 = al((size_t)16 * 32 * 961 * 4);
  size_t o_cp2 = al((size_t)16 * 961 * 4);
  size_t o_b3 = al(16 * 4);
  size_t o_ll = al(NLMN * 4), o_lm_ = al(NLMN * 4), o_ln = al(NLMN * 4);
  size_t o_lml = al(NLM * 4), o_lmm = al(NLM * 4);
  size_t total = pos;
  std::vector<char> blob(total, 0);

  c2* dft64 = (c2*)(blob.data() + o_dft64);
  for (int m15 = 0; m15 < 31; ++m15) {
    int m = m15 - 15;
    for (int a = 0; a < 64; ++a) {
      double ang = -2.0 * M_PI * a * m / 64.0;
      dft64[m15 * 64 + a] = make_float2((float)cos(ang), (float)sin(ang));
    }
  }
  c2* dft32 = (c2*)(blob.data() + o_dft32);
  c2* idft32 = (c2*)(blob.data() + o_idft32);
  for (int m15 = 0; m15 < 31; ++m15) {
    int m = m15 - 15;
    for (int a = 0; a < 32; ++a) {
      double ang = -2.0 * M_PI * a * m / 32.0;
      dft32[m15 * 32 + a] = make_float2((float)cos(ang), (float)sin(ang));
      double angi = 2.0 * M_PI * a * m / 32.0;
      idft32[m15 * 32 + a] = make_float2((float)cos(angi), (float)sin(angi));
    }
  }

  const double S2S = 1.0 / sqrt(768.0);    // 1/sqrt(2*32*12)
  const double SO3S = 1.0 / sqrt(1024.0);  // 1/sqrt(2*16*32)
  double qw32[64], qw16[32], beta32[64], beta16[32];
  quad_w(32, qw32);
  quad_w(16, qw16);
  for (int k = 0; k < 64; ++k) beta32[k] = M_PI * (2 * k + 1) / 128.0;
  for (int k = 0; k < 32; ++k) beta16[k] = M_PI * (2 * k + 1) / 64.0;

  float* cf1 = (float*)(blob.data() + o_cf1);
  float* cp1 = (float*)(blob.data() + o_cp1);
  float* cd1 = (float*)(blob.data() + o_cd1);
  float* cw2 = (float*)(blob.data() + o_cw2);
  float* cp2 = (float*)(blob.data() + o_cp2);
  std::vector<double> dbuf(31 * 31);

  for (int l = 0; l < 16; ++l) {
    int tl = 2 * l + 1;
    for (int z = 0; z < 64; ++z) {
      wig_d(l, beta32[z], dbuf.data());
      for (int m = -l; m <= l; ++m)
        cf1[(size_t)(l * 31 + (m + 15)) * 64 + z] = (float)(qw32[z] * dbuf[(m + l) * tl + l]);
    }
    wig_d(l, M_PI / 2, dbuf.data());
    for (int n = -l; n <= l; ++n)
      cp1[l * 31 + (n + 15)] = (float)(S2S * dbuf[(n + l) * tl + l]);
    for (int k = -l; k <= l; ++k)
      for (int n = -l; n <= l; ++n)
        cp2[((size_t)l * 31 + (k + 15)) * 31 + (n + 15)] = (float)(SO3S * dbuf[(k + l) * tl + (n + l)]);
    for (int z = 0; z < 32; ++z) {
      wig_d(l, beta16[z], dbuf.data());
      for (int m = -l; m <= l; ++m)
        for (int n = -l; n <= l; ++n) {
          double d = dbuf[(m + l) * tl + (n + l)];
          size_t idx = (size_t)(l * 32 + z) * 961 + (m + 15) * 31 + (n + 15);
          cd1[idx] = (float)((2 * l + 1) * d);
          cw2[idx] = (float)(qw16[z] * d);
        }
    }
  }

  int* b3 = (int*)(blob.data() + o_b3);
  int* ll = (int*)(blob.data() + o_ll);
  int* lmv = (int*)(blob.data() + o_lm_);
  int* ln = (int*)(blob.data() + o_ln);
  int* lml = (int*)(blob.data() + o_lml);
  int* lmm = (int*)(blob.data() + o_lmm);
  int idx = 0;
  for (int l = 0; l < 16; ++l) {
    b3[l] = idx;
    for (int a = 0; a < 2 * l + 1; ++a)
      for (int c = 0; c < 2 * l + 1; ++c) {
        ll[idx] = l; lmv[idx] = (a - l) + 15; ln[idx] = (c - l) + 15; ++idx;
      }
  }
  int idx2 = 0;
  for (int l = 0; l < 16; ++l)
    for (int a = 0; a < 2 * l + 1; ++a) { lml[idx2] = l; lmm[idx2] = (a - l) + 15; ++idx2; }

  void* dev = nullptr;
  if (hipMalloc(&dev, total) != hipSuccess) return;
  if (hipMemcpy(dev, blob.data(), total, hipMemcpyHostToDevice) != hipSuccess) return;
  char* base = (char*)dev;
  g.dft64 = (c2*)(base + o_dft64);
  g.dft32 = (c2*)(base + o_dft32);
  g.idft32 = (c2*)(base + o_idft32);
  g.cf1 = (float*)(base + o_cf1);
  g.cp1 = (float*)(base + o_cp1);
  g.cd1 = (float*)(base + o_cd1);
  g.cw2 = (float*)(base + o_cw2);
  g.cp2 = (float*)(base + o_cp2);
  g.base3 = (int*)(base + o_b3);
  g.lmn_l = (int*)(base + o_ll);
  g.lmn_m = (int*)(base + o_lm_);
  g.lmn_n = (int*)(base + o_ln);
  g.lm_l = (int*)(base + o_lml);
  g.lm_m = (int*)(base + o_lmm);
  g_base = dev;
}

struct Boot { Boot() { build_and_upload(); } };
Boot s_boot;

}  // namespace

// ---------------------------------------------------------------------------
extern "C" void kernel_launch(void* const* d_in, const int* in_sizes, int n_in,
                              void* d_out, int out_size, void* d_ws, size_t ws_size,
                              hipStream_t stream) {
  (void)in_sizes; (void)n_in; (void)out_size; (void)ws_size;
  if (!g_base) build_and_upload();

  const float* x = (const float*)d_in[0];
  const float* w_s2 = (const float*)d_in[1];
  const float* b_s2 = (const float*)d_in[2];
  const float* w_so3 = (const float*)d_in[3];
  const float* b_so3 = (const float*)d_in[4];
  float* out = (float*)d_out;
  c2* W = (c2*)d_ws;

  // ---------------- S2 conv ----------------
  {
    c2* xf1 = W;                  // 190464
    c2* wh1 = W + 190464;         // 11904
    c2* X1  = W + 202368;         // 24576
    c2* Z1  = W + 226944;         // 1396736 (end 1623680 = 13 MB)

    k_s2_fft<<<dim3(6144), dim3(64), 0, stream>>>(x, xf1, g.dft64);
    k_wfft<<<dim3((31 * 384 + 255) / 256), dim3(256), 0, stream>>>(w_s2, wh1, g.dft64, 384, 64);
    k_X1<<<dim3((NLM * 96 + 255) / 256), dim3(256), 0, stream>>>(xf1, X1, g.cf1, g.lm_l, g.lm_m);
    k_Z1<<<dim3((256 * NLMN + 255) / 256), dim3(256), 0, stream>>>(X1, wh1, Z1, g.cp1,
                                                                   g.lmn_l, g.lmn_m, g.lmn_n);
    // fused scatter + idft2: 256 bo x 4 z-chunks
    k_syn<<<dim3(256 * ZCH), dim3(256), 0, stream>>>(Z1, out, b_s2, g.idft32, g.cd1, 32);
  }

  // ---------------- SO3 conv ----------------
  {
    c2* xf2 = W;                   // 7872512  (overlaps S2 scratch; stream-ordered)
    c2* X2  = W + 7872512;         // 1396736
    c2* wh2 = W + 9269248;         // 63488
    c2* U   = W + 9332736;         // 2793472
    c2* Z2  = W + 12126208;        // 2793472 (end 14919680 = 119 MB)

    k_wfft<<<dim3((31 * 2048 + 255) / 256), dim3(256), 0, stream>>>(w_so3, wh2, g.dft32, 2048, 32);
    // fused relu + 2D DFT: one block per (b,i,z) image
    k_fft2<<<dim3(8192), dim3(256), 0, stream>>>(out, xf2, g.dft32);
    int t3 = 8 * 32 * NLMN;
    k_X2<<<dim3((t3 + 255) / 256), dim3(256), 0, stream>>>(xf2, X2, g.cw2,
                                                           g.lmn_l, g.lmn_m, g.lmn_n, t3);
    int tU = 512 * NLMN;
    k_U<<<dim3((tU + 255) / 256), dim3(256), 0, stream>>>(X2, wh2, U, g.lmn_n, tU);
    k_Z2<<<dim3((tU + 255) / 256), dim3(256), 0, stream>>>(U, Z2, g.cp2,
                                                           g.lmn_l, g.lmn_m, g.lmn_n, g.base3, tU);
    // fused scatter + idft2: 512 bo x 4 z-chunks
    k_syn<<<dim3(512 * ZCH), dim3(256), 0, stream>>>(Z2, out + 8388608, b_so3, g.idft32, g.cd1, 64);
  }
}

// Round 7
// 892.008 us; speedup vs baseline: 1.7378x; 1.7378x over previous
//
#include <hip/hip_runtime.h>
#include <cmath>
#include <cstdint>
#include <cstring>
#include <vector>
#include <algorithm>

#ifndef M_PI
#define M_PI 3.14159265358979323846
#endif

typedef float2 c2;
#define NLMN 5456   // sum_{l<16} (2l+1)^2
#define NLM  256    // sum_{l<16} (2l+1)

__device__ __forceinline__ c2 cmad(c2 acc, c2 a, c2 b) {
  acc.x = fmaf(a.x, b.x, fmaf(-a.y, b.y, acc.x));
  acc.y = fmaf(a.x, b.y, fmaf( a.y, b.x, acc.y));
  return acc;
}

// ---------------------------------------------------------------------------
// K1: xf1[row=(b*12+i)*64+z][m15] = (1/64) sum_a x[row][a] * e^{-2pi i a m/64}
__global__ void k_s2_fft(const float* __restrict__ x, c2* __restrict__ xf1,
                         const c2* __restrict__ dft64) {
  __shared__ float row[64];
  int r = blockIdx.x;
  row[threadIdx.x] = x[(size_t)r * 64 + threadIdx.x];
  __syncthreads();
  int m = threadIdx.x;
  if (m < 31) {
    float ax = 0.f, ay = 0.f;
    #pragma unroll
    for (int a = 0; a < 64; ++a) {
      c2 e = dft64[m * 64 + a];
      float v = row[a];
      ax = fmaf(v, e.x, ax); ay = fmaf(v, e.y, ay);
    }
    xf1[(size_t)r * 31 + m] = make_float2(ax * (1.f / 64.f), ay * (1.f / 64.f));
  }
}

// K2: wh[m15][io] = sum_j w[io][j] * tab[m15][j]
__global__ __launch_bounds__(256) void k_wfft(const float* __restrict__ w,
                       c2* __restrict__ wh, const c2* __restrict__ tab,
                       int IO, int J) {
  int t = blockIdx.x * blockDim.x + threadIdx.x;
  if (t >= 31 * IO) return;
  int m = t / IO, io = t - m * IO;
  float ax = 0.f, ay = 0.f;
  for (int j = 0; j < J; ++j) {
    float v = w[(size_t)io * J + j];
    c2 e = tab[m * J + j];
    ax = fmaf(v, e.x, ax); ay = fmaf(v, e.y, ay);
  }
  wh[t] = make_float2(ax, ay);
}

// K3: X1[lm][b*12+i] = sum_z cf1[l][m15][z] * xf1[(b*12+i)*64+z][m15]
__global__ __launch_bounds__(256) void k_X1(const c2* __restrict__ xf1,
                     c2* __restrict__ X1, const float* __restrict__ cf1,
                     const int* __restrict__ lm_l, const int* __restrict__ lm_m) {
  int t = blockIdx.x * blockDim.x + threadIdx.x;
  if (t >= NLM * 96) return;
  int lm = t / 96, bi = t - lm * 96;
  int l = lm_l[lm], m15 = lm_m[lm];
  const float* cf = cf1 + (size_t)(l * 31 + m15) * 64;
  const c2* xp = xf1 + (size_t)bi * 64 * 31 + m15;
  float ax = 0.f, ay = 0.f;
  #pragma unroll 8
  for (int z = 0; z < 64; ++z) {
    float wg = cf[z];
    c2 v = xp[(size_t)z * 31];
    ax = fmaf(wg, v.x, ax); ay = fmaf(wg, v.y, ay);
  }
  X1[t] = make_float2(ax, ay);
}

// K4: Z1[bo][lmn] = cp1[l][n15] * sum_i X1[lm][b][i] * wh1[n15][i*32+o]
__global__ __launch_bounds__(256) void k_Z1(const c2* __restrict__ X1,
                     const c2* __restrict__ wh1, c2* __restrict__ Z1,
                     const float* __restrict__ cp1,
                     const int* __restrict__ lmn_l, const int* __restrict__ lmn_m,
                     const int* __restrict__ lmn_n) {
  int t = blockIdx.x * blockDim.x + threadIdx.x;
  if (t >= 256 * NLMN) return;
  int bo = t / NLMN, lmn = t - bo * NLMN;
  int b = bo >> 5, o = bo & 31;
  int l = lmn_l[lmn], m15 = lmn_m[lmn], n15 = lmn_n[lmn];
  int lm = l * l + (m15 - 15 + l);
  float s = cp1[l * 31 + n15];
  c2 acc = make_float2(0.f, 0.f);
  const c2* xp = X1 + (size_t)(lm * 8 + b) * 12;
  const c2* wp = wh1 + (size_t)n15 * 384 + o;
  #pragma unroll
  for (int i = 0; i < 12; ++i) acc = cmad(acc, xp[i], wp[(size_t)i * 32]);
  Z1[t] = make_float2(acc.x * s, acc.y * s);
}

// ---------------------------------------------------------------------------
// K_SYN v2: fused scatter + 2D inverse DFT + bias, Hermitian-half.
// One block per (bo, z). out is mathematically real => freq[-m,-n]=conj(freq[m,n]),
// so only m>=0 is computed; stage2 doubles the m>0 contributions.
__global__ __launch_bounds__(256) void k_syn(const c2* __restrict__ Z,
                        float* __restrict__ out, const float* __restrict__ bias,
                        const c2* __restrict__ idft32, const float* __restrict__ cd,
                        int O) {
  __shared__ c2 fqh[496];   // [mh 0..15][n15 0..30], m = mh >= 0
  __shared__ c2 Tm[512];    // [mh][q]
  __shared__ c2 tab[992];   // [i][j] = e^{+2pi i (i-15) j / 32}
  int bo = blockIdx.x >> 5;
  int z = blockIdx.x & 31;
  int tid = threadIdx.x;
  float bv = bias[bo % O];
  for (int k = tid; k < 992; k += 256) tab[k] = idft32[k];
  const c2* Zbo = Z + (size_t)bo * NLMN;
  // ---- scatter: fqh[mh][n15] = sum_{l>=lmin} cd[l][z][m15=mh+15][n15] * Z[bo][l,mh,n]
  for (int k = tid; k < 496; k += 256) {
    int mh = k / 31, n15 = k - mh * 31;
    int n = n15 - 15;
    int an = n < 0 ? -n : n;
    int lmin = mh > an ? mh : an;
    float ax = 0.f, ay = 0.f;
    for (int l = lmin; l < 16; ++l) {
      float d = cd[(size_t)(l * 32 + z) * 961 + (mh + 15) * 31 + n15];
      int b3 = (4 * l * l * l - l) / 3;            // sum_{j<l}(2j+1)^2
      c2 zv = Zbo[b3 + (mh + l) * (2 * l + 1) + (n + l)];
      ax = fmaf(d, zv.x, ax); ay = fmaf(d, zv.y, ay);
    }
    fqh[k] = make_float2(ax, ay);
  }
  __syncthreads();
  // ---- stage 1: Tm[mh][q] = sum_n fqh[mh][n15] * tab[n15][q]
  for (int k = tid; k < 512; k += 256) {
    int mh = k >> 5, q = k & 31;
    const c2* fr = fqh + mh * 31;
    c2 acc = make_float2(0.f, 0.f);
    #pragma unroll
    for (int n = 0; n < 31; ++n) acc = cmad(acc, fr[n], tab[n * 32 + q]);
    Tm[k] = acc;
  }
  __syncthreads();
  // ---- stage 2: out[p][q] = Re(Tm[0][q]) + 2 sum_{mh>0} Re(tab[mh+15][p] * Tm[mh][q])
  {
    int pp = tid >> 4, qq = tid & 15;
    float c0 = 0.5f * Tm[qq].x, c1 = 0.5f * Tm[qq + 16].x;
    float r00 = c0, r01 = c1, r10 = c0, r11 = c1;
    #pragma unroll
    for (int mh = 1; mh < 16; ++mh) {
      c2 tp0 = tab[(mh + 15) * 32 + pp];
      c2 tp1 = tab[(mh + 15) * 32 + pp + 16];
      c2 q0 = Tm[mh * 32 + qq];
      c2 q1 = Tm[mh * 32 + qq + 16];
      r00 = fmaf(tp0.x, q0.x, fmaf(-tp0.y, q0.y, r00));
      r01 = fmaf(tp0.x, q1.x, fmaf(-tp0.y, q1.y, r01));
      r10 = fmaf(tp1.x, q0.x, fmaf(-tp1.y, q0.y, r10));
      r11 = fmaf(tp1.x, q1.x, fmaf(-tp1.y, q1.y, r11));
    }
    float* ob = out + ((size_t)bo * 32 + z) * 1024;
    ob[pp * 32 + qq] = 2.f * r00 + bv;
    ob[pp * 32 + qq + 16] = 2.f * r01 + bv;
    ob[(pp + 16) * 32 + qq] = 2.f * r10 + bv;
    ob[(pp + 16) * 32 + qq + 16] = 2.f * r11 + bv;
  }
}

// ---------------------------------------------------------------------------
// K_FFT2 v2: fused relu + 2D DFT (32x32 -> 31x31), one image per block.
// Real input => G[a][-n] = conj(G[a][n]) and xf2[-m][-n] = conj(xf2[m][n]):
// compute half, mirror the rest.
__global__ __launch_bounds__(256) void k_fft2(const float* __restrict__ x1,
                       c2* __restrict__ xf2, const c2* __restrict__ dft32) {
  __shared__ float f[1024];
  __shared__ c2 G[992];      // [a][n15]
  __shared__ c2 tab[992];    // [m15][a]  (dft32 row-major)
  __shared__ c2 tabT[512];   // [g][nh]   nh = n 0..15 (transposed, stage A)
  int img = blockIdx.x;
  int tid = threadIdx.x;
  const float* xp = x1 + (size_t)img * 1024;
  for (int k = tid; k < 1024; k += 256) { float v = xp[k]; f[k] = v > 0.f ? v : 0.f; }
  for (int k = tid; k < 992; k += 256) tab[k] = dft32[k];
  for (int k = tid; k < 512; k += 256) {
    int g2 = k >> 4, nh = k & 15;
    tabT[k] = dft32[(nh + 15) * 32 + g2];
  }
  __syncthreads();
  // stage A (half): G[a][15+nh] = sum_g f[a][g] * e^{-2pi i g nh/32}, nh = 0..15
  for (int k = tid; k < 512; k += 256) {
    int a = k >> 4, nh = k & 15;
    const float* fr = f + a * 32;
    float ax = 0.f, ay = 0.f;
    #pragma unroll
    for (int g2 = 0; g2 < 32; ++g2) {
      c2 e = tabT[g2 * 16 + nh];
      ax = fmaf(fr[g2], e.x, ax); ay = fmaf(fr[g2], e.y, ay);
    }
    G[a * 31 + 15 + nh] = make_float2(ax, ay);
  }
  __syncthreads();
  // mirror: G[a][n15<15] = conj(G[a][30-n15])
  for (int k = tid; k < 480; k += 256) {
    int a = k / 15, j = k - a * 15;
    c2 v = G[a * 31 + 30 - j];
    G[a * 31 + j] = make_float2(v.x, -v.y);
  }
  __syncthreads();
  // stage B (half): F[m][n] = (1/1024) sum_a e^{-2pi i a(m-15)/32} * G[a][n]
  // computed for m>0 (m15 16..30, all n15) plus m=0 (m15=15, n15 15..30); mirror conj.
  c2* op = xf2 + (size_t)img * 961;
  for (int k = tid; k < 481; k += 256) {
    int m15, n15;
    if (k < 465) { m15 = 16 + k / 31; n15 = k - (k / 31) * 31; }
    else { m15 = 15; n15 = k - 465 + 15; }
    const c2* tm2 = tab + m15 * 32;
    c2 acc = make_float2(0.f, 0.f);
    #pragma unroll
    for (int a = 0; a < 32; ++a) acc = cmad(acc, tm2[a], G[a * 31 + n15]);
    acc.x *= (1.f / 1024.f); acc.y *= (1.f / 1024.f);
    op[m15 * 31 + n15] = acc;
    op[(30 - m15) * 31 + (30 - n15)] = make_float2(acc.x, -acc.y);
  }
}

// K9: X2[(b*32+i)][lmn] = sum_z cw2[l][z][mn] * xf2[bi][z][mn]
__global__ __launch_bounds__(256) void k_X2(const c2* __restrict__ xf2,
                     c2* __restrict__ X2, const float* __restrict__ cw2,
                     const int* __restrict__ lmn_l, const int* __restrict__ lmn_m,
                     const int* __restrict__ lmn_n, int total) {
  int t = blockIdx.x * blockDim.x + threadIdx.x;
  if (t >= total) return;
  int lmn = t % NLMN;
  int bi = t / NLMN;
  int l = lmn_l[lmn], m15 = lmn_m[lmn], n15 = lmn_n[lmn];
  int mn = m15 * 31 + n15;
  const c2* xp = xf2 + (size_t)bi * 32 * 961 + mn;
  const float* cw = cw2 + (size_t)l * 32 * 961 + mn;
  float ax = 0.f, ay = 0.f;
  for (int z = 0; z < 32; ++z) {
    float wg = cw[(size_t)z * 961];
    c2 v = xp[(size_t)z * 961];
    ax = fmaf(wg, v.x, ax); ay = fmaf(wg, v.y, ay);
  }
  X2[(size_t)bi * NLMN + lmn] = make_float2(ax, ay);
}

// K10: U[bo][lmk] = sum_i X2[b][i][lmk] * wh2[k15][i*64+o]
__global__ __launch_bounds__(256) void k_U(const c2* __restrict__ X2,
                    const c2* __restrict__ wh2, c2* __restrict__ U,
                    const int* __restrict__ lmn_n, int total) {
  int t = blockIdx.x * blockDim.x + threadIdx.x;
  if (t >= total) return;
  int lmk = t % NLMN;
  int bo = t / NLMN;
  int b = bo >> 6, o = bo & 63;
  int k15 = lmn_n[lmk];
  const c2* xp = X2 + (size_t)b * 32 * NLMN + lmk;
  const c2* wp = wh2 + (size_t)k15 * 2048 + o;
  c2 acc = make_float2(0.f, 0.f);
  #pragma unroll 8
  for (int i = 0; i < 32; ++i) acc = cmad(acc, xp[(size_t)i * NLMN], wp[(size_t)i * 64]);
  U[t] = acc;
}

// K11: Z2[bo][lmn] = sum_k U[bo][lmk] * cp2[l][k15][n15]
__global__ __launch_bounds__(256) void k_Z2(const c2* __restrict__ U,
                     c2* __restrict__ Z2, const float* __restrict__ cp2,
                     const int* __restrict__ lmn_l, const int* __restrict__ lmn_m,
                     const int* __restrict__ lmn_n, const int* __restrict__ base3,
                     int total) {
  int t = blockIdx.x * blockDim.x + threadIdx.x;
  if (t >= total) return;
  int lmn = t % NLMN;
  int bo = t / NLMN;
  int l = lmn_l[lmn], m15 = lmn_m[lmn], n15 = lmn_n[lmn];
  int tl = 2 * l + 1;
  const c2* up = U + (size_t)bo * NLMN + base3[l] + (m15 - 15 + l) * tl;
  const float* cp = cp2 + ((size_t)l * 31 + (15 - l)) * 31 + n15;
  float ax = 0.f, ay = 0.f;
  for (int kk = 0; kk < tl; ++kk) {
    float s = cp[(size_t)kk * 31];
    c2 uv = up[kk];
    ax = fmaf(s, uv.x, ax); ay = fmaf(s, uv.y, ay);
  }
  Z2[t] = make_float2(ax, ay);
}

// ---------------------------------------------------------------------------
namespace {

struct DC {
  c2 *dft64, *dft32, *idft32;
  float *cf1, *cp1, *cd1, *cw2, *cp2;
  int *base3, *lmn_l, *lmn_m, *lmn_n, *lm_l, *lm_m;
};
DC g{};
void* g_base = nullptr;
double s_fact[64];

void wig_d(int l, double beta, double* out) {
  int n = 2 * l + 1;
  double cb = cos(beta * 0.5), sb = sin(beta * 0.5);
  for (int a = 0; a < n; ++a) {
    int mp = a - l;
    for (int b = 0; b < n; ++b) {
      int m = b - l;
      double pref = sqrt(s_fact[l + mp] * s_fact[l - mp] * s_fact[l + m] * s_fact[l - m]);
      int smin = std::max(0, m - mp);
      int smax = std::min(l + m, l - mp);
      double sum = 0.0;
      for (int s = smin; s <= smax; ++s) {
        double denom = s_fact[l + m - s] * s_fact[s] * s_fact[mp - m + s] * s_fact[l - mp - s];
        double sign = ((mp - m + s) & 1) ? -1.0 : 1.0;
        sum += sign / denom * std::pow(cb, 2 * l + m - mp - 2 * s)
                            * std::pow(sb, mp - m + 2 * s);
      }
      out[a * n + b] = pref * sum;
    }
  }
}

void quad_w(int b, double* w) {
  for (int k = 0; k < 2 * b; ++k) {
    double th = M_PI * (2.0 * k + 1.0) / (4.0 * b);
    double s = 0;
    for (int j = 0; j < b; ++j) s += sin(th * (2 * j + 1)) / (2 * j + 1);
    w[k] = 2.0 / b * sin(th) * s;
  }
}

void build_and_upload() {
  if (g_base) return;
  s_fact[0] = 1;
  for (int i = 1; i < 64; ++i) s_fact[i] = s_fact[i - 1] * i;

  size_t pos = 0;
  auto al = [&](size_t b) { pos = (pos + 15) & ~(size_t)15; size_t r = pos; pos += b; return r; };
  size_t o_dft64 = al(31 * 64 * sizeof(c2));
  size_t o_dft32 = al(31 * 32 * sizeof(c2));
  size_t o_idft32 = al(31 * 32 * sizeof(c2));
  size_t o_cf1 = al(16 * 31 * 64 * 4);
  size_t o_cp1 = al(16 * 31 * 4);
  size_t o_cd1 = al((size_t)16 * 32 * 961 * 4);
  size_t o_cw2 = al((size_t)16 * 32 * 961 * 4);
  size_t o_cp2 = al((size_t)16 * 961 * 4);
  size_t o_b3 = al(16 * 4);
  size_t o_ll = al(NLMN * 4), o_lm_ = al(NLMN * 4), o_ln = al(NLMN * 4);
  size_t o_lml = al(NLM * 4), o_lmm = al(NLM * 4);
  size_t total = pos;
  std::vector<char> blob(total, 0);

  c2* dft64 = (c2*)(blob.data() + o_dft64);
  for (int m15 = 0; m15 < 31; ++m15) {
    int m = m15 - 15;
    for (int a = 0; a < 64; ++a) {
      double ang = -2.0 * M_PI * a * m / 64.0;
      dft64[m15 * 64 + a] = make_float2((float)cos(ang), (float)sin(ang));
    }
  }
  c2* dft32 = (c2*)(blob.data() + o_dft32);
  c2* idft32 = (c2*)(blob.data() + o_idft32);
  for (int m15 = 0; m15 < 31; ++m15) {
    int m = m15 - 15;
    for (int a = 0; a < 32; ++a) {
      double ang = -2.0 * M_PI * a * m / 32.0;
      dft32[m15 * 32 + a] = make_float2((float)cos(ang), (float)sin(ang));
      double angi = 2.0 * M_PI * a * m / 32.0;
      idft32[m15 * 32 + a] = make_float2((float)cos(angi), (float)sin(angi));
    }
  }

  const double S2S = 1.0 / sqrt(768.0);    // 1/sqrt(2*32*12)
  const double SO3S = 1.0 / sqrt(1024.0);  // 1/sqrt(2*16*32)
  double qw32[64], qw16[32], beta32[64], beta16[32];
  quad_w(32, qw32);
  quad_w(16, qw16);
  for (int k = 0; k < 64; ++k) beta32[k] = M_PI * (2 * k + 1) / 128.0;
  for (int k = 0; k < 32; ++k) beta16[k] = M_PI * (2 * k + 1) / 64.0;

  float* cf1 = (float*)(blob.data() + o_cf1);
  float* cp1 = (float*)(blob.data() + o_cp1);
  float* cd1 = (float*)(blob.data() + o_cd1);
  float* cw2 = (float*)(blob.data() + o_cw2);
  float* cp2 = (float*)(blob.data() + o_cp2);
  std::vector<double> dbuf(31 * 31);

  for (int l = 0; l < 16; ++l) {
    int tl = 2 * l + 1;
    for (int z = 0; z < 64; ++z) {
      wig_d(l, beta32[z], dbuf.data());
      for (int m = -l; m <= l; ++m)
        cf1[(size_t)(l * 31 + (m + 15)) * 64 + z] = (float)(qw32[z] * dbuf[(m + l) * tl + l]);
    }
    wig_d(l, M_PI / 2, dbuf.data());
    for (int n = -l; n <= l; ++n)
      cp1[l * 31 + (n + 15)] = (float)(S2S * dbuf[(n + l) * tl + l]);
    for (int k = -l; k <= l; ++k)
      for (int n = -l; n <= l; ++n)
        cp2[((size_t)l * 31 + (k + 15)) * 31 + (n + 15)] = (float)(SO3S * dbuf[(k + l) * tl + (n + l)]);
    for (int z = 0; z < 32; ++z) {
      wig_d(l, beta16[z], dbuf.data());
      for (int m = -l; m <= l; ++m)
        for (int n = -l; n <= l; ++n) {
          double d = dbuf[(m + l) * tl + (n + l)];
          size_t idx = (size_t)(l * 32 + z) * 961 + (m + 15) * 31 + (n + 15);
          cd1[idx] = (float)((2 * l + 1) * d);
          cw2[idx] = (float)(qw16[z] * d);
        }
    }
  }

  int* b3 = (int*)(blob.data() + o_b3);
  int* ll = (int*)(blob.data() + o_ll);
  int* lmv = (int*)(blob.data() + o_lm_);
  int* ln = (int*)(blob.data() + o_ln);
  int* lml = (int*)(blob.data() + o_lml);
  int* lmm = (int*)(blob.data() + o_lmm);
  int idx = 0;
  for (int l = 0; l < 16; ++l) {
    b3[l] = idx;
    for (int a = 0; a < 2 * l + 1; ++a)
      for (int c = 0; c < 2 * l + 1; ++c) {
        ll[idx] = l; lmv[idx] = (a - l) + 15; ln[idx] = (c - l) + 15; ++idx;
      }
  }
  int idx2 = 0;
  for (int l = 0; l < 16; ++l)
    for (int a = 0; a < 2 * l + 1; ++a) { lml[idx2] = l; lmm[idx2] = (a - l) + 15; ++idx2; }

  void* dev = nullptr;
  if (hipMalloc(&dev, total) != hipSuccess) return;
  if (hipMemcpy(dev, blob.data(), total, hipMemcpyHostToDevice) != hipSuccess) return;
  char* base = (char*)dev;
  g.dft64 = (c2*)(base + o_dft64);
  g.dft32 = (c2*)(base + o_dft32);
  g.idft32 = (c2*)(base + o_idft32);
  g.cf1 = (float*)(base + o_cf1);
  g.cp1 = (float*)(base + o_cp1);
  g.cd1 = (float*)(base + o_cd1);
  g.cw2 = (float*)(base + o_cw2);
  g.cp2 = (float*)(base + o_cp2);
  g.base3 = (int*)(base + o_b3);
  g.lmn_l = (int*)(base + o_ll);
  g.lmn_m = (int*)(base + o_lm_);
  g.lmn_n = (int*)(base + o_ln);
  g.lm_l = (int*)(base + o_lml);
  g.lm_m = (int*)(base + o_lmm);
  g_base = dev;
}

struct Boot { Boot() { build_and_upload(); } };
Boot s_boot;

}  // namespace

// ---------------------------------------------------------------------------
extern "C" void kernel_launch(void* const* d_in, const int* in_sizes, int n_in,
                              void* d_out, int out_size, void* d_ws, size_t ws_size,
                              hipStream_t stream) {
  (void)in_sizes; (void)n_in; (void)out_size; (void)ws_size;
  if (!g_base) build_and_upload();

  const float* x = (const float*)d_in[0];
  const float* w_s2 = (const float*)d_in[1];
  const float* b_s2 = (const float*)d_in[2];
  const float* w_so3 = (const float*)d_in[3];
  const float* b_so3 = (const float*)d_in[4];
  float* out = (float*)d_out;
  c2* W = (c2*)d_ws;

  // ---------------- S2 conv ----------------
  {
    c2* xf1 = W;                  // 190464
    c2* wh1 = W + 190464;         // 11904
    c2* X1  = W + 202368;         // 24576
    c2* Z1  = W + 226944;         // 1396736 (end 1623680 = 13 MB)

    k_s2_fft<<<dim3(6144), dim3(64), 0, stream>>>(x, xf1, g.dft64);
    k_wfft<<<dim3((31 * 384 + 255) / 256), dim3(256), 0, stream>>>(w_s2, wh1, g.dft64, 384, 64);
    k_X1<<<dim3((NLM * 96 + 255) / 256), dim3(256), 0, stream>>>(xf1, X1, g.cf1, g.lm_l, g.lm_m);
    k_Z1<<<dim3((256 * NLMN + 255) / 256), dim3(256), 0, stream>>>(X1, wh1, Z1, g.cp1,
                                                                   g.lmn_l, g.lmn_m, g.lmn_n);
    // fused scatter + idft2: one block per (bo, z)
    k_syn<<<dim3(256 * 32), dim3(256), 0, stream>>>(Z1, out, b_s2, g.idft32, g.cd1, 32);
  }

  // ---------------- SO3 conv ----------------
  {
    c2* xf2 = W;                   // 7872512  (overlaps S2 scratch; stream-ordered)
    c2* X2  = W + 7872512;         // 1396736
    c2* wh2 = W + 9269248;         // 63488
    c2* U   = W + 9332736;         // 2793472
    c2* Z2  = W + 12126208;        // 2793472 (end 14919680 = 119 MB)

    k_wfft<<<dim3((31 * 2048 + 255) / 256), dim3(256), 0, stream>>>(w_so3, wh2, g.dft32, 2048, 32);
    // fused relu + 2D DFT: one block per (b,i,z) image
    k_fft2<<<dim3(8192), dim3(256), 0, stream>>>(out, xf2, g.dft32);
    int t3 = 8 * 32 * NLMN;
    k_X2<<<dim3((t3 + 255) / 256), dim3(256), 0, stream>>>(xf2, X2, g.cw2,
                                                           g.lmn_l, g.lmn_m, g.lmn_n, t3);
    int tU = 512 * NLMN;
    k_U<<<dim3((tU + 255) / 256), dim3(256), 0, stream>>>(X2, wh2, U, g.lmn_n, tU);
    k_Z2<<<dim3((tU + 255) / 256), dim3(256), 0, stream>>>(U, Z2, g.cp2,
                                                           g.lmn_l, g.lmn_m, g.lmn_n, g.base3, tU);
    // fused scatter + idft2: one block per (bo, z)
    k_syn<<<dim3(512 * 32), dim3(256), 0, stream>>>(Z2, out + 8388608, b_so3, g.idft32, g.cd1, 64);
  }
}

// Round 10
// 881.954 us; speedup vs baseline: 1.7576x; 1.0114x over previous
//
#include <hip/hip_runtime.h>
#include <cmath>
#include <cstdint>
#include <cstring>
#include <vector>
#include <algorithm>

#ifndef M_PI
#define M_PI 3.14159265358979323846
#endif

typedef float2 c2;
#define NLMN 5456   // sum_{l<16} (2l+1)^2
#define NLM  256    // sum_{l<16} (2l+1)

__device__ __forceinline__ c2 cmad(c2 acc, c2 a, c2 b) {
  acc.x = fmaf(a.x, b.x, fmaf(-a.y, b.y, acc.x));
  acc.y = fmaf(a.x, b.y, fmaf( a.y, b.x, acc.y));
  return acc;
}

// ---------------------------------------------------------------------------
// K1: xf1[row=(b*12+i)*64+z][m15] = (1/64) sum_a x[row][a] * e^{-2pi i a m/64}
__global__ void k_s2_fft(const float* __restrict__ x, c2* __restrict__ xf1,
                         const c2* __restrict__ dft64) {
  __shared__ float row[64];
  int r = blockIdx.x;
  row[threadIdx.x] = x[(size_t)r * 64 + threadIdx.x];
  __syncthreads();
  int m = threadIdx.x;
  if (m < 31) {
    float ax = 0.f, ay = 0.f;
    #pragma unroll
    for (int a = 0; a < 64; ++a) {
      c2 e = dft64[m * 64 + a];
      float v = row[a];
      ax = fmaf(v, e.x, ax); ay = fmaf(v, e.y, ay);
    }
    xf1[(size_t)r * 31 + m] = make_float2(ax * (1.f / 64.f), ay * (1.f / 64.f));
  }
}

// K2: wh[m15][io] = sum_j w[io][j] * tab[m15][j]
__global__ __launch_bounds__(256) void k_wfft(const float* __restrict__ w,
                       c2* __restrict__ wh, const c2* __restrict__ tab,
                       int IO, int J) {
  int t = blockIdx.x * blockDim.x + threadIdx.x;
  if (t >= 31 * IO) return;
  int m = t / IO, io = t - m * IO;
  float ax = 0.f, ay = 0.f;
  for (int j = 0; j < J; ++j) {
    float v = w[(size_t)io * J + j];
    c2 e = tab[m * J + j];
    ax = fmaf(v, e.x, ax); ay = fmaf(v, e.y, ay);
  }
  wh[t] = make_float2(ax, ay);
}

// K3: X1[lm][b*12+i] = sum_z cf1[l][m15][z] * xf1[(b*12+i)*64+z][m15]
__global__ __launch_bounds__(256) void k_X1(const c2* __restrict__ xf1,
                     c2* __restrict__ X1, const float* __restrict__ cf1,
                     const int* __restrict__ lm_l, const int* __restrict__ lm_m) {
  int t = blockIdx.x * blockDim.x + threadIdx.x;
  if (t >= NLM * 96) return;
  int lm = t / 96, bi = t - lm * 96;
  int l = lm_l[lm], m15 = lm_m[lm];
  const float* cf = cf1 + (size_t)(l * 31 + m15) * 64;
  const c2* xp = xf1 + (size_t)bi * 64 * 31 + m15;
  float ax = 0.f, ay = 0.f;
  #pragma unroll 8
  for (int z = 0; z < 64; ++z) {
    float wg = cf[z];
    c2 v = xp[(size_t)z * 31];
    ax = fmaf(wg, v.x, ax); ay = fmaf(wg, v.y, ay);
  }
  X1[t] = make_float2(ax, ay);
}

// K4: Z1[bo][lmn] = cp1[l][n15] * sum_i X1[lm][b][i] * wh1[n15][i*32+o]
__global__ __launch_bounds__(256) void k_Z1(const c2* __restrict__ X1,
                     const c2* __restrict__ wh1, c2* __restrict__ Z1,
                     const float* __restrict__ cp1,
                     const int* __restrict__ lmn_l, const int* __restrict__ lmn_m,
                     const int* __restrict__ lmn_n) {
  int t = blockIdx.x * blockDim.x + threadIdx.x;
  if (t >= 256 * NLMN) return;
  int bo = t / NLMN, lmn = t - bo * NLMN;
  int b = bo >> 5, o = bo & 31;
  int l = lmn_l[lmn], m15 = lmn_m[lmn], n15 = lmn_n[lmn];
  int lm = l * l + (m15 - 15 + l);
  float s = cp1[l * 31 + n15];
  c2 acc = make_float2(0.f, 0.f);
  const c2* xp = X1 + (size_t)(lm * 8 + b) * 12;
  const c2* wp = wh1 + (size_t)n15 * 384 + o;
  #pragma unroll
  for (int i = 0; i < 12; ++i) acc = cmad(acc, xp[i], wp[(size_t)i * 32]);
  Z1[t] = make_float2(acc.x * s, acc.y * s);
}

// ---------------------------------------------------------------------------
// K_SYN v2: fused scatter + 2D inverse DFT + bias, Hermitian-half.
// One block per (bo, z). out is mathematically real => freq[-m,-n]=conj(freq[m,n]),
// so only m>=0 is computed; stage2 doubles the m>0 contributions.
// __launch_bounds__(256, 8): force VGPR<=64 so 8 blocks/CU (32 waves) fit —
// R7 profile showed VGPR=84 capping occupancy at 33% (latency-bound scatter).
__global__ __launch_bounds__(256, 8) void k_syn(const c2* __restrict__ Z,
                        float* __restrict__ out, const float* __restrict__ bias,
                        const c2* __restrict__ idft32, const float* __restrict__ cd,
                        int O) {
  __shared__ c2 fqh[496];   // [mh 0..15][n15 0..30], m = mh >= 0
  __shared__ c2 Tm[512];    // [mh][q]
  __shared__ c2 tab[992];   // [i][j] = e^{+2pi i (i-15) j / 32}
  int bo = blockIdx.x >> 5;
  int z = blockIdx.x & 31;
  int tid = threadIdx.x;
  float bv = bias[bo % O];
  for (int k = tid; k < 992; k += 256) tab[k] = idft32[k];
  const c2* Zbo = Z + (size_t)bo * NLMN;
  // ---- scatter: fqh[mh][n15] = sum_{l>=lmin} cd[l][z][m15=mh+15][n15] * Z[bo][l,mh,n]
  for (int k = tid; k < 496; k += 256) {
    int mh = k / 31, n15 = k - mh * 31;
    int n = n15 - 15;
    int an = n < 0 ? -n : n;
    int lmin = mh > an ? mh : an;
    float ax = 0.f, ay = 0.f;
    for (int l = lmin; l < 16; ++l) {
      float d = cd[(size_t)(l * 32 + z) * 961 + (mh + 15) * 31 + n15];
      int b3 = (4 * l * l * l - l) / 3;            // sum_{j<l}(2j+1)^2
      c2 zv = Zbo[b3 + (mh + l) * (2 * l + 1) + (n + l)];
      ax = fmaf(d, zv.x, ax); ay = fmaf(d, zv.y, ay);
    }
    fqh[k] = make_float2(ax, ay);
  }
  __syncthreads();
  // ---- stage 1: Tm[mh][q] = sum_n fqh[mh][n15] * tab[n15][q]
  for (int k = tid; k < 512; k += 256) {
    int mh = k >> 5, q = k & 31;
    const c2* fr = fqh + mh * 31;
    c2 acc = make_float2(0.f, 0.f);
    #pragma unroll
    for (int n = 0; n < 31; ++n) acc = cmad(acc, fr[n], tab[n * 32 + q]);
    Tm[k] = acc;
  }
  __syncthreads();
  // ---- stage 2: out[p][q] = Re(Tm[0][q]) + 2 sum_{mh>0} Re(tab[mh+15][p] * Tm[mh][q])
  {
    int pp = tid >> 4, qq = tid & 15;
    float c0 = 0.5f * Tm[qq].x, c1 = 0.5f * Tm[qq + 16].x;
    float r00 = c0, r01 = c1, r10 = c0, r11 = c1;
    #pragma unroll
    for (int mh = 1; mh < 16; ++mh) {
      c2 tp0 = tab[(mh + 15) * 32 + pp];
      c2 tp1 = tab[(mh + 15) * 32 + pp + 16];
      c2 q0 = Tm[mh * 32 + qq];
      c2 q1 = Tm[mh * 32 + qq + 16];
      r00 = fmaf(tp0.x, q0.x, fmaf(-tp0.y, q0.y, r00));
      r01 = fmaf(tp0.x, q1.x, fmaf(-tp0.y, q1.y, r01));
      r10 = fmaf(tp1.x, q0.x, fmaf(-tp1.y, q0.y, r10));
      r11 = fmaf(tp1.x, q1.x, fmaf(-tp1.y, q1.y, r11));
    }
    float* ob = out + ((size_t)bo * 32 + z) * 1024;
    ob[pp * 32 + qq] = 2.f * r00 + bv;
    ob[pp * 32 + qq + 16] = 2.f * r01 + bv;
    ob[(pp + 16) * 32 + qq] = 2.f * r10 + bv;
    ob[(pp + 16) * 32 + qq + 16] = 2.f * r11 + bv;
  }
}

// ---------------------------------------------------------------------------
// K_FFT2 v2: fused relu + 2D DFT (32x32 -> 31x31), one image per block.
// Real input => G[a][-n] = conj(G[a][n]) and xf2[-m][-n] = conj(xf2[m][n]):
// compute half, mirror the rest.
__global__ __launch_bounds__(256) void k_fft2(const float* __restrict__ x1,
                       c2* __restrict__ xf2, const c2* __restrict__ dft32) {
  __shared__ float f[1024];
  __shared__ c2 G[992];      // [a][n15]
  __shared__ c2 tab[992];    // [m15][a]  (dft32 row-major)
  __shared__ c2 tabT[512];   // [g][nh]   nh = n 0..15 (transposed, stage A)
  int img = blockIdx.x;
  int tid = threadIdx.x;
  const float* xp = x1 + (size_t)img * 1024;
  for (int k = tid; k < 1024; k += 256) { float v = xp[k]; f[k] = v > 0.f ? v : 0.f; }
  for (int k = tid; k < 992; k += 256) tab[k] = dft32[k];
  for (int k = tid; k < 512; k += 256) {
    int g2 = k >> 4, nh = k & 15;
    tabT[k] = dft32[(nh + 15) * 32 + g2];
  }
  __syncthreads();
  // stage A (half): G[a][15+nh] = sum_g f[a][g] * e^{-2pi i g nh/32}, nh = 0..15
  for (int k = tid; k < 512; k += 256) {
    int a = k >> 4, nh = k & 15;
    const float* fr = f + a * 32;
    float ax = 0.f, ay = 0.f;
    #pragma unroll
    for (int g2 = 0; g2 < 32; ++g2) {
      c2 e = tabT[g2 * 16 + nh];
      ax = fmaf(fr[g2], e.x, ax); ay = fmaf(fr[g2], e.y, ay);
    }
    G[a * 31 + 15 + nh] = make_float2(ax, ay);
  }
  __syncthreads();
  // mirror: G[a][n15<15] = conj(G[a][30-n15])
  for (int k = tid; k < 480; k += 256) {
    int a = k / 15, j = k - a * 15;
    c2 v = G[a * 31 + 30 - j];
    G[a * 31 + j] = make_float2(v.x, -v.y);
  }
  __syncthreads();
  // stage B (half): F[m][n] = (1/1024) sum_a e^{-2pi i a(m-15)/32} * G[a][n]
  // computed for m>0 (m15 16..30, all n15) plus m=0 (m15=15, n15 15..30); mirror conj.
  c2* op = xf2 + (size_t)img * 961;
  for (int k = tid; k < 481; k += 256) {
    int m15, n15;
    if (k < 465) { m15 = 16 + k / 31; n15 = k - (k / 31) * 31; }
    else { m15 = 15; n15 = k - 465 + 15; }
    const c2* tm2 = tab + m15 * 32;
    c2 acc = make_float2(0.f, 0.f);
    #pragma unroll
    for (int a = 0; a < 32; ++a) acc = cmad(acc, tm2[a], G[a * 31 + n15]);
    acc.x *= (1.f / 1024.f); acc.y *= (1.f / 1024.f);
    op[m15 * 31 + n15] = acc;
    op[(30 - m15) * 31 + (30 - n15)] = make_float2(acc.x, -acc.y);
  }
}

// K9: X2[(b*32+i)][lmn] = sum_z cw2[l][z][mn] * xf2[bi][z][mn]
__global__ __launch_bounds__(256) void k_X2(const c2* __restrict__ xf2,
                     c2* __restrict__ X2, const float* __restrict__ cw2,
                     const int* __restrict__ lmn_l, const int* __restrict__ lmn_m,
                     const int* __restrict__ lmn_n, int total) {
  int t = blockIdx.x * blockDim.x + threadIdx.x;
  if (t >= total) return;
  int lmn = t % NLMN;
  int bi = t / NLMN;
  int l = lmn_l[lmn], m15 = lmn_m[lmn], n15 = lmn_n[lmn];
  int mn = m15 * 31 + n15;
  const c2* xp = xf2 + (size_t)bi * 32 * 961 + mn;
  const float* cw = cw2 + (size_t)l * 32 * 961 + mn;
  float ax = 0.f, ay = 0.f;
  for (int z = 0; z < 32; ++z) {
    float wg = cw[(size_t)z * 961];
    c2 v = xp[(size_t)z * 961];
    ax = fmaf(wg, v.x, ax); ay = fmaf(wg, v.y, ay);
  }
  X2[(size_t)bi * NLMN + lmn] = make_float2(ax, ay);
}

// K10: U[bo][lmk] = sum_i X2[b][i][lmk] * wh2[k15][i*64+o]
__global__ __launch_bounds__(256) void k_U(const c2* __restrict__ X2,
                    const c2* __restrict__ wh2, c2* __restrict__ U,
                    const int* __restrict__ lmn_n, int total) {
  int t = blockIdx.x * blockDim.x + threadIdx.x;
  if (t >= total) return;
  int lmk = t % NLMN;
  int bo = t / NLMN;
  int b = bo >> 6, o = bo & 63;
  int k15 = lmn_n[lmk];
  const c2* xp = X2 + (size_t)b * 32 * NLMN + lmk;
  const c2* wp = wh2 + (size_t)k15 * 2048 + o;
  c2 acc = make_float2(0.f, 0.f);
  #pragma unroll 8
  for (int i = 0; i < 32; ++i) acc = cmad(acc, xp[(size_t)i * NLMN], wp[(size_t)i * 64]);
  U[t] = acc;
}

// K11: Z2[bo][lmn] = sum_k U[bo][lmk] * cp2[l][k15][n15]
__global__ __launch_bounds__(256) void k_Z2(const c2* __restrict__ U,
                     c2* __restrict__ Z2, const float* __restrict__ cp2,
                     const int* __restrict__ lmn_l, const int* __restrict__ lmn_m,
                     const int* __restrict__ lmn_n, const int* __restrict__ base3,
                     int total) {
  int t = blockIdx.x * blockDim.x + threadIdx.x;
  if (t >= total) return;
  int lmn = t % NLMN;
  int bo = t / NLMN;
  int l = lmn_l[lmn], m15 = lmn_m[lmn], n15 = lmn_n[lmn];
  int tl = 2 * l + 1;
  const c2* up = U + (size_t)bo * NLMN + base3[l] + (m15 - 15 + l) * tl;
  const float* cp = cp2 + ((size_t)l * 31 + (15 - l)) * 31 + n15;
  float ax = 0.f, ay = 0.f;
  for (int kk = 0; kk < tl; ++kk) {
    float s = cp[(size_t)kk * 31];
    c2 uv = up[kk];
    ax = fmaf(s, uv.x, ax); ay = fmaf(s, uv.y, ay);
  }
  Z2[t] = make_float2(ax, ay);
}

// ---------------------------------------------------------------------------
namespace {

struct DC {
  c2 *dft64, *dft32, *idft32;
  float *cf1, *cp1, *cd1, *cw2, *cp2;
  int *base3, *lmn_l, *lmn_m, *lmn_n, *lm_l, *lm_m;
};
DC g{};
void* g_base = nullptr;
double s_fact[64];

void wig_d(int l, double beta, double* out) {
  int n = 2 * l + 1;
  double cb = cos(beta * 0.5), sb = sin(beta * 0.5);
  for (int a = 0; a < n; ++a) {
    int mp = a - l;
    for (int b = 0; b < n; ++b) {
      int m = b - l;
      double pref = sqrt(s_fact[l + mp] * s_fact[l - mp] * s_fact[l + m] * s_fact[l - m]);
      int smin = std::max(0, m - mp);
      int smax = std::min(l + m, l - mp);
      double sum = 0.0;
      for (int s = smin; s <= smax; ++s) {
        double denom = s_fact[l + m - s] * s_fact[s] * s_fact[mp - m + s] * s_fact[l - mp - s];
        double sign = ((mp - m + s) & 1) ? -1.0 : 1.0;
        sum += sign / denom * std::pow(cb, 2 * l + m - mp - 2 * s)
                            * std::pow(sb, mp - m + 2 * s);
      }
      out[a * n + b] = pref * sum;
    }
  }
}

void quad_w(int b, double* w) {
  for (int k = 0; k < 2 * b; ++k) {
    double th = M_PI * (2.0 * k + 1.0) / (4.0 * b);
    double s = 0;
    for (int j = 0; j < b; ++j) s += sin(th * (2 * j + 1)) / (2 * j + 1);
    w[k] = 2.0 / b * sin(th) * s;
  }
}

void build_and_upload() {
  if (g_base) return;
  s_fact[0] = 1;
  for (int i = 1; i < 64; ++i) s_fact[i] = s_fact[i - 1] * i;

  size_t pos = 0;
  auto al = [&](size_t b) { pos = (pos + 15) & ~(size_t)15; size_t r = pos; pos += b; return r; };
  size_t o_dft64 = al(31 * 64 * sizeof(c2));
  size_t o_dft32 = al(31 * 32 * sizeof(c2));
  size_t o_idft32 = al(31 * 32 * sizeof(c2));
  size_t o_cf1 = al(16 * 31 * 64 * 4);
  size_t o_cp1 = al(16 * 31 * 4);
  size_t o_cd1 = al((size_t)16 * 32 * 961 * 4);
  size_t o_cw2 = al((size_t)16 * 32 * 961 * 4);
  size_t o_cp2 = al((size_t)16 * 961 * 4);
  size_t o_b3 = al(16 * 4);
  size_t o_ll = al(NLMN * 4), o_lm_ = al(NLMN * 4), o_ln = al(NLMN * 4);
  size_t o_lml = al(NLM * 4), o_lmm = al(NLM * 4);
  size_t total = pos;
  std::vector<char> blob(total, 0);

  c2* dft64 = (c2*)(blob.data() + o_dft64);
  for (int m15 = 0; m15 < 31; ++m15) {
    int m = m15 - 15;
    for (int a = 0; a < 64; ++a) {
      double ang = -2.0 * M_PI * a * m / 64.0;
      dft64[m15 * 64 + a] = make_float2((float)cos(ang), (float)sin(ang));
    }
  }
  c2* dft32 = (c2*)(blob.data() + o_dft32);
  c2* idft32 = (c2*)(blob.data() + o_idft32);
  for (int m15 = 0; m15 < 31; ++m15) {
    int m = m15 - 15;
    for (int a = 0; a < 32; ++a) {
      double ang = -2.0 * M_PI * a * m / 32.0;
      dft32[m15 * 32 + a] = make_float2((float)cos(ang), (float)sin(ang));
      double angi = 2.0 * M_PI * a * m / 32.0;
      idft32[m15 * 32 + a] = make_float2((float)cos(angi), (float)sin(angi));
    }
  }

  const double S2S = 1.0 / sqrt(768.0);    // 1/sqrt(2*32*12)
  const double SO3S = 1.0 / sqrt(1024.0);  // 1/sqrt(2*16*32)
  double qw32[64], qw16[32], beta32[64], beta16[32];
  quad_w(32, qw32);
  quad_w(16, qw16);
  for (int k = 0; k < 64; ++k) beta32[k] = M_PI * (2 * k + 1) / 128.0;
  for (int k = 0; k < 32; ++k) beta16[k] = M_PI * (2 * k + 1) / 64.0;

  float* cf1 = (float*)(blob.data() + o_cf1);
  float* cp1 = (float*)(blob.data() + o_cp1);
  float* cd1 = (float*)(blob.data() + o_cd1);
  float* cw2 = (float*)(blob.data() + o_cw2);
  float* cp2 = (float*)(blob.data() + o_cp2);
  std::vector<double> dbuf(31 * 31);

  for (int l = 0; l < 16; ++l) {
    int tl = 2 * l + 1;
    for (int z = 0; z < 64; ++z) {
      wig_d(l, beta32[z], dbuf.data());
      for (int m = -l; m <= l; ++m)
        cf1[(size_t)(l * 31 + (m + 15)) * 64 + z] = (float)(qw32[z] * dbuf[(m + l) * tl + l]);
    }
    wig_d(l, M_PI / 2, dbuf.data());
    for (int n = -l; n <= l; ++n)
      cp1[l * 31 + (n + 15)] = (float)(S2S * dbuf[(n + l) * tl + l]);
    for (int k = -l; k <= l; ++k)
      for (int n = -l; n <= l; ++n)
        cp2[((size_t)l * 31 + (k + 15)) * 31 + (n + 15)] = (float)(SO3S * dbuf[(k + l) * tl + (n + l)]);
    for (int z = 0; z < 32; ++z) {
      wig_d(l, beta16[z], dbuf.data());
      for (int m = -l; m <= l; ++m)
        for (int n = -l; n <= l; ++n) {
          double d = dbuf[(m + l) * tl + (n + l)];
          size_t idx = (size_t)(l * 32 + z) * 961 + (m + 15) * 31 + (n + 15);
          cd1[idx] = (float)((2 * l + 1) * d);
          cw2[idx] = (float)(qw16[z] * d);
        }
    }
  }

  int* b3 = (int*)(blob.data() + o_b3);
  int* ll = (int*)(blob.data() + o_ll);
  int* lmv = (int*)(blob.data() + o_lm_);
  int* ln = (int*)(blob.data() + o_ln);
  int* lml = (int*)(blob.data() + o_lml);
  int* lmm = (int*)(blob.data() + o_lmm);
  int idx = 0;
  for (int l = 0; l < 16; ++l) {
    b3[l] = idx;
    for (int a = 0; a < 2 * l + 1; ++a)
      for (int c = 0; c < 2 * l + 1; ++c) {
        ll[idx] = l; lmv[idx] = (a - l) + 15; ln[idx] = (c - l) + 15; ++idx;
      }
  }
  int idx2 = 0;
  for (int l = 0; l < 16; ++l)
    for (int a = 0; a < 2 * l + 1; ++a) { lml[idx2] = l; lmm[idx2] = (a - l) + 15; ++idx2; }

  void* dev = nullptr;
  if (hipMalloc(&dev, total) != hipSuccess) return;
  if (hipMemcpy(dev, blob.data(), total, hipMemcpyHostToDevice) != hipSuccess) return;
  char* base = (char*)dev;
  g.dft64 = (c2*)(base + o_dft64);
  g.dft32 = (c2*)(base + o_dft32);
  g.idft32 = (c2*)(base + o_idft32);
  g.cf1 = (float*)(base + o_cf1);
  g.cp1 = (float*)(base + o_cp1);
  g.cd1 = (float*)(base + o_cd1);
  g.cw2 = (float*)(base + o_cw2);
  g.cp2 = (float*)(base + o_cp2);
  g.base3 = (int*)(base + o_b3);
  g.lmn_l = (int*)(base + o_ll);
  g.lmn_m = (int*)(base + o_lm_);
  g.lmn_n = (int*)(base + o_ln);
  g.lm_l = (int*)(base + o_lml);
  g.lm_m = (int*)(base + o_lmm);
  g_base = dev;
}

struct Boot { Boot() { build_and_upload(); } };
Boot s_boot;

}  // namespace

// ---------------------------------------------------------------------------
extern "C" void kernel_launch(void* const* d_in, const int* in_sizes, int n_in,
                              void* d_out, int out_size, void* d_ws, size_t ws_size,
                              hipStream_t stream) {
  (void)in_sizes; (void)n_in; (void)out_size; (void)ws_size;
  if (!g_base) build_and_upload();

  const float* x = (const float*)d_in[0];
  const float* w_s2 = (const float*)d_in[1];
  const float* b_s2 = (const float*)d_in[2];
  const float* w_so3 = (const float*)d_in[3];
  const float* b_so3 = (const float*)d_in[4];
  float* out = (float*)d_out;
  c2* W = (c2*)d_ws;

  // ---------------- S2 conv ----------------
  {
    c2* xf1 = W;                  // 190464
    c2* wh1 = W + 190464;         // 11904
    c2* X1  = W + 202368;         // 24576
    c2* Z1  = W + 226944;         // 1396736 (end 1623680 = 13 MB)

    k_s2_fft<<<dim3(6144), dim3(64), 0, stream>>>(x, xf1, g.dft64);
    k_wfft<<<dim3((31 * 384 + 255) / 256), dim3(256), 0, stream>>>(w_s2, wh1, g.dft64, 384, 64);
    k_X1<<<dim3((NLM * 96 + 255) / 256), dim3(256), 0, stream>>>(xf1, X1, g.cf1, g.lm_l, g.lm_m);
    k_Z1<<<dim3((256 * NLMN + 255) / 256), dim3(256), 0, stream>>>(X1, wh1, Z1, g.cp1,
                                                                   g.lmn_l, g.lmn_m, g.lmn_n);
    // fused scatter + idft2: one block per (bo, z)
    k_syn<<<dim3(256 * 32), dim3(256), 0, stream>>>(Z1, out, b_s2, g.idft32, g.cd1, 32);
  }

  // ---------------- SO3 conv ----------------
  {
    c2* xf2 = W;                   // 7872512  (overlaps S2 scratch; stream-ordered)
    c2* X2  = W + 7872512;         // 1396736
    c2* wh2 = W + 9269248;         // 63488
    c2* U   = W + 9332736;         // 2793472
    c2* Z2  = W + 12126208;        // 2793472 (end 14919680 = 119 MB)

    k_wfft<<<dim3((31 * 2048 + 255) / 256), dim3(256), 0, stream>>>(w_so3, wh2, g.dft32, 2048, 32);
    // fused relu + 2D DFT: one block per (b,i,z) image
    k_fft2<<<dim3(8192), dim3(256), 0, stream>>>(out, xf2, g.dft32);
    int t3 = 8 * 32 * NLMN;
    k_X2<<<dim3((t3 + 255) / 256), dim3(256), 0, stream>>>(xf2, X2, g.cw2,
                                                           g.lmn_l, g.lmn_m, g.lmn_n, t3);
    int tU = 512 * NLMN;
    k_U<<<dim3((tU + 255) / 256), dim3(256), 0, stream>>>(X2, wh2, U, g.lmn_n, tU);
    k_Z2<<<dim3((tU + 255) / 256), dim3(256), 0, stream>>>(U, Z2, g.cp2,
                                                           g.lmn_l, g.lmn_m, g.lmn_n, g.base3, tU);
    // fused scatter + idft2: one block per (bo, z)
    k_syn<<<dim3(512 * 32), dim3(256), 0, stream>>>(Z2, out + 8388608, b_so3, g.idft32, g.cd1, 64);
  }
}